// Round 1
// baseline (152.229 us; speedup 1.0000x reference)
//
#include <hip/hip_runtime.h>
#include <math.h>

#define NOUT 512
#define NIN  1024
#define HID  32
#define NB   256
#define TOPK 6

// One block per output unit o (512 blocks), one thread per batch element b (256 threads).
// Round 1: fp64 accumulation everywhere to rule out sign-flip precision failures
// (output is sign(logit); a flipped sign is absmax=2 vs threshold=0.02).
__global__ __launch_bounds__(256, 2) void blayer_kernel(
    const float* __restrict__ inputs,  // (B, IN)
    const float* __restrict__ mask,    // (OUT, IN)
    const float* __restrict__ W1,      // (OUT, IN, HID)
    const float* __restrict__ W2,      // (OUT, HID, HID)
    const float* __restrict__ W3,      // (OUT, HID, HID)
    const float* __restrict__ W4,      // (OUT, HID, 1)
    float* __restrict__ out)           // (B, OUT)
{
    const int o = blockIdx.x;
    const int t = threadIdx.x;

    __shared__ float  vals[NIN];
    __shared__ int    sidx[TOPK];
    __shared__ double w1s[TOPK][HID];
    __shared__ double w2s[HID * HID];
    __shared__ double w3s[HID * HID];
    __shared__ double w4s[HID];
    __shared__ float  red_v[4];
    __shared__ int    red_i[4];

    // ---- stage mask row ----
    const float* mrow = mask + (size_t)o * NIN;
#pragma unroll
    for (int k = 0; k < NIN / NB; ++k) vals[t + NB * k] = mrow[t + NB * k];
    __syncthreads();

    // ---- top-6 via iterative argmax (set semantics; order irrelevant) ----
    for (int it = 0; it < TOPK; ++it) {
        float bv = -INFINITY;
        int   bi = 0;
#pragma unroll
        for (int k = 0; k < NIN / NB; ++k) {
            float v = vals[t + NB * k];
            if (v > bv) { bv = v; bi = t + NB * k; }
        }
        // wave64 butterfly-free down-reduce
#pragma unroll
        for (int off = 32; off > 0; off >>= 1) {
            float ov = __shfl_down(bv, off);
            int   oi = __shfl_down(bi, off);
            if (ov > bv) { bv = ov; bi = oi; }
        }
        if ((t & 63) == 0) { red_v[t >> 6] = bv; red_i[t >> 6] = bi; }
        __syncthreads();
        if (t == 0) {
            float fv = red_v[0]; int fi = red_i[0];
            for (int w = 1; w < 4; ++w)
                if (red_v[w] > fv) { fv = red_v[w]; fi = red_i[w]; }
            sidx[it] = fi;
            vals[fi] = -INFINITY;   // exclude for next iteration
        }
        __syncthreads();
    }

    // ---- stage weights for this o (convert to double in LDS) ----
    if (t < TOPK * HID) {
        int j = t >> 5, h = t & 31;
        w1s[j][h] = (double)W1[((size_t)o * NIN + sidx[j]) * HID + h];
    }
    {
        const float* w2p = W2 + (size_t)o * HID * HID;
        const float* w3p = W3 + (size_t)o * HID * HID;
#pragma unroll
        for (int k = 0; k < (HID * HID) / NB; ++k) {
            w2s[t + NB * k] = (double)w2p[t + NB * k];
            w3s[t + NB * k] = (double)w3p[t + NB * k];
        }
    }
    if (t < HID) w4s[t] = (double)W4[(size_t)o * HID + t];
    __syncthreads();

    // ---- per-thread 4-layer MLP for batch element b = t ----
    double xin[TOPK];
#pragma unroll
    for (int j = 0; j < TOPK; ++j)
        xin[j] = (double)inputs[(size_t)t * NIN + sidx[j]];

    double h1[HID], h2[HID];

    // layer 1: (6) x (6 x 32)
#pragma unroll
    for (int h = 0; h < HID; ++h) {
        double acc = 0.0;
#pragma unroll
        for (int j = 0; j < TOPK; ++j) acc = fma(xin[j], w1s[j][h], acc);
        h1[h] = acc > 0.0 ? acc : 0.0;
    }

    // layer 2: (32) x (32 x 32)
#pragma unroll 4
    for (int k = 0; k < HID; ++k) {
        double acc = 0.0;
#pragma unroll
        for (int h = 0; h < HID; ++h) acc = fma(h1[h], w2s[h * HID + k], acc);
        h2[k] = acc > 0.0 ? acc : 0.0;
    }

    // layer 3: (32) x (32 x 32) — reuse h1 as h3
#pragma unroll 4
    for (int k = 0; k < HID; ++k) {
        double acc = 0.0;
#pragma unroll
        for (int h = 0; h < HID; ++h) acc = fma(h2[h], w3s[h * HID + k], acc);
        h1[k] = acc > 0.0 ? acc : 0.0;
    }

    // layer 4: dot(32) ; sigmoid(z) >= 0.5  <=>  z >= 0
    double z = 0.0;
#pragma unroll
    for (int h = 0; h < HID; ++h) z = fma(h1[h], w4s[h], z);

    out[(size_t)t * NOUT + o] = (z >= 0.0) ? 1.0f : -1.0f;
}

extern "C" void kernel_launch(void* const* d_in, const int* in_sizes, int n_in,
                              void* d_out, int out_size, void* d_ws, size_t ws_size,
                              hipStream_t stream) {
    const float* inputs = (const float*)d_in[0];
    const float* mask   = (const float*)d_in[1];
    const float* W1     = (const float*)d_in[2];
    const float* W2     = (const float*)d_in[3];
    const float* W3     = (const float*)d_in[4];
    const float* W4     = (const float*)d_in[5];
    float* out = (float*)d_out;

    blayer_kernel<<<dim3(NOUT), dim3(NB), 0, stream>>>(
        inputs, mask, W1, W2, W3, W4, out);
}

// Round 2
// 127.230 us; speedup vs baseline: 1.1965x; 1.1965x over previous
//
#include <hip/hip_runtime.h>
#include <math.h>

#define NOUT 512
#define NIN  1024
#define HID  32
#define NB   256
#define TOPK 6

// One block per output unit o (512 blocks), one thread per batch element b (256 threads).
// Round 2: full unroll (no dynamic register-array indexing -> no scratch spill),
// fp32 math with fp64 final dot, scalar (wave-uniform) weight loads.
__global__ __launch_bounds__(256, 2) void blayer_kernel(
    const float* __restrict__ inputs,  // (B, IN)
    const float* __restrict__ mask,    // (OUT, IN)
    const float* __restrict__ W1,      // (OUT, IN, HID)
    const float* __restrict__ W2,      // (OUT, HID, HID)
    const float* __restrict__ W3,      // (OUT, HID, HID)
    const float* __restrict__ W4,      // (OUT, HID, 1)
    float* __restrict__ out)           // (B, OUT)
{
    const int o = blockIdx.x;
    const int t = threadIdx.x;

    __shared__ float vals[NIN];
    __shared__ int   sidx[TOPK];
    __shared__ float red_v[4];
    __shared__ int   red_i[4];

    // ---- stage mask row ----
    const float* mrow = mask + (size_t)o * NIN;
#pragma unroll
    for (int k = 0; k < NIN / NB; ++k) vals[t + NB * k] = mrow[t + NB * k];
    __syncthreads();

    // ---- top-6 via iterative argmax (set semantics; order irrelevant) ----
    for (int it = 0; it < TOPK; ++it) {
        float bv = -INFINITY;
        int   bi = 0;
#pragma unroll
        for (int k = 0; k < NIN / NB; ++k) {
            float v = vals[t + NB * k];
            if (v > bv) { bv = v; bi = t + NB * k; }
        }
#pragma unroll
        for (int off = 32; off > 0; off >>= 1) {
            float ov = __shfl_down(bv, off);
            int   oi = __shfl_down(bi, off);
            if (ov > bv) { bv = ov; bi = oi; }
        }
        if ((t & 63) == 0) { red_v[t >> 6] = bv; red_i[t >> 6] = bi; }
        __syncthreads();
        if (t == 0) {
            float fv = red_v[0]; int fi = red_i[0];
            for (int w = 1; w < 4; ++w)
                if (red_v[w] > fv) { fv = red_v[w]; fi = red_i[w]; }
            sidx[it] = fi;
            vals[fi] = -INFINITY;
        }
        __syncthreads();
    }

    // ---- broadcast selected indices to SGPRs (wave-uniform) ----
    int sj[TOPK];
#pragma unroll
    for (int j = 0; j < TOPK; ++j)
        sj[j] = __builtin_amdgcn_readfirstlane(sidx[j]);

    // ---- gather gated inputs for this thread's batch element (issue early) ----
    float xin[TOPK];
#pragma unroll
    for (int j = 0; j < TOPK; ++j)
        xin[j] = inputs[(size_t)t * NIN + sj[j]];

    const float* W1b = W1 + (size_t)o * NIN * HID;
    const float* W2b = W2 + (size_t)o * HID * HID;
    const float* W3b = W3 + (size_t)o * HID * HID;
    const float* W4b = W4 + (size_t)o * HID;

    float h[HID], acc[HID];

    // ---- layer 1: (6) x (6 x 32), row-major weight rows (uniform, contiguous) ----
#pragma unroll
    for (int k = 0; k < HID; ++k) acc[k] = 0.0f;
#pragma unroll
    for (int j = 0; j < TOPK; ++j) {
        const float* w1r = W1b + (size_t)sj[j] * HID;
        const float  xj  = xin[j];
#pragma unroll
        for (int k = 0; k < HID; ++k) acc[k] = fmaf(xj, w1r[k], acc[k]);
    }
#pragma unroll
    for (int k = 0; k < HID; ++k) h[k] = acc[k] > 0.0f ? acc[k] : 0.0f;

    // ---- layer 2: h-outer / k-inner, contiguous uniform weight rows ----
#pragma unroll
    for (int k = 0; k < HID; ++k) acc[k] = 0.0f;
#pragma unroll
    for (int hh = 0; hh < HID; ++hh) {
        const float hv = h[hh];
        const float* wr = W2b + hh * HID;
#pragma unroll
        for (int k = 0; k < HID; ++k) acc[k] = fmaf(hv, wr[k], acc[k]);
    }
#pragma unroll
    for (int k = 0; k < HID; ++k) h[k] = acc[k] > 0.0f ? acc[k] : 0.0f;

    // ---- layer 3 ----
#pragma unroll
    for (int k = 0; k < HID; ++k) acc[k] = 0.0f;
#pragma unroll
    for (int hh = 0; hh < HID; ++hh) {
        const float hv = h[hh];
        const float* wr = W3b + hh * HID;
#pragma unroll
        for (int k = 0; k < HID; ++k) acc[k] = fmaf(hv, wr[k], acc[k]);
    }
#pragma unroll
    for (int k = 0; k < HID; ++k) h[k] = acc[k] > 0.0f ? acc[k] : 0.0f;

    // ---- layer 4: fp64 dot as cheap sign insurance; sigmoid(z)>=0.5 <=> z>=0 ----
    double z = 0.0;
#pragma unroll
    for (int k = 0; k < HID; ++k) z = fma((double)h[k], (double)W4b[k], z);

    out[(size_t)t * NOUT + o] = (z >= 0.0) ? 1.0f : -1.0f;
}

extern "C" void kernel_launch(void* const* d_in, const int* in_sizes, int n_in,
                              void* d_out, int out_size, void* d_ws, size_t ws_size,
                              hipStream_t stream) {
    const float* inputs = (const float*)d_in[0];
    const float* mask   = (const float*)d_in[1];
    const float* W1     = (const float*)d_in[2];
    const float* W2     = (const float*)d_in[3];
    const float* W3     = (const float*)d_in[4];
    const float* W4     = (const float*)d_in[5];
    float* out = (float*)d_out;

    blayer_kernel<<<dim3(NOUT), dim3(NB), 0, stream>>>(
        inputs, mask, W1, W2, W3, W4, out);
}

// Round 3
// 121.157 us; speedup vs baseline: 1.2565x; 1.0501x over previous
//
#include <hip/hip_runtime.h>
#include <math.h>

#define NOUT 512
#define NIN  1024
#define HID  32
#define BATCH 256
#define NT   128
#define TOPK 6

// One block per output unit o (512 blocks), 128 threads; each thread handles
// batch elements b = t and b = t+128 (each LDS weight read feeds 8 FMAs).
// Weights staged in LDS (float4), read via wave-uniform ds_read_b128 broadcast,
// consumed by VGPR-operand v_fmac (no SGPR prefetch-window limit).
__global__ __launch_bounds__(NT, 1) void blayer_kernel(
    const float* __restrict__ inputs,  // (B, IN)
    const float* __restrict__ mask,    // (OUT, IN)
    const float* __restrict__ W1,      // (OUT, IN, HID)
    const float* __restrict__ W2,      // (OUT, HID, HID)
    const float* __restrict__ W3,      // (OUT, HID, HID)
    const float* __restrict__ W4,      // (OUT, HID, 1)
    float* __restrict__ out)           // (B, OUT)
{
    const int o = blockIdx.x;
    const int t = threadIdx.x;

    __shared__ float  vals[NIN];
    __shared__ int    sidx[TOPK];
    __shared__ float  red_v[NT / 64];
    __shared__ int    red_i[NT / 64];
    __shared__ float4 w1s[TOPK * 8];   // 6 x 32
    __shared__ float4 w2s[256];        // 32 x 32
    __shared__ float4 w3s[256];        // 32 x 32
    __shared__ float4 w4s[8];          // 32

    // ---- stage W2/W3/W4 into LDS (independent of top-k; latency overlaps it) ----
    {
        const float4* W2f = (const float4*)(W2 + (size_t)o * HID * HID);
        const float4* W3f = (const float4*)(W3 + (size_t)o * HID * HID);
        w2s[t]       = W2f[t];
        w2s[t + NT]  = W2f[t + NT];
        w3s[t]       = W3f[t];
        w3s[t + NT]  = W3f[t + NT];
        if (t < 8) w4s[t] = ((const float4*)(W4 + (size_t)o * HID))[t];
    }

    // ---- stage mask row ----
    const float* mrow = mask + (size_t)o * NIN;
#pragma unroll
    for (int k = 0; k < NIN / NT; ++k) vals[t + NT * k] = mrow[t + NT * k];
    __syncthreads();

    // ---- top-6 via iterative argmax ----
    for (int it = 0; it < TOPK; ++it) {
        float bv = -INFINITY;
        int   bi = 0;
#pragma unroll
        for (int k = 0; k < NIN / NT; ++k) {
            float v = vals[t + NT * k];
            if (v > bv) { bv = v; bi = t + NT * k; }
        }
#pragma unroll
        for (int off = 32; off > 0; off >>= 1) {
            float ov = __shfl_down(bv, off);
            int   oi = __shfl_down(bi, off);
            if (ov > bv) { bv = ov; bi = oi; }
        }
        if ((t & 63) == 0) { red_v[t >> 6] = bv; red_i[t >> 6] = bi; }
        __syncthreads();
        if (t == 0) {
            float fv = red_v[0]; int fi = red_i[0];
            if (red_v[1] > fv) { fv = red_v[1]; fi = red_i[1]; }
            sidx[it] = fi;
            vals[fi] = -INFINITY;
        }
        __syncthreads();
    }

    // ---- broadcast indices; stage selected W1 rows; gather inputs ----
    int sj[TOPK];
#pragma unroll
    for (int j = 0; j < TOPK; ++j)
        sj[j] = __builtin_amdgcn_readfirstlane(sidx[j]);

    if (t < TOPK * 8) {
        int j = t >> 3, q = t & 7;
        const float4* r = (const float4*)(W1 + ((size_t)o * NIN + sj[j]) * HID);
        w1s[t] = r[q];
    }

    float x0[TOPK], x1[TOPK];
#pragma unroll
    for (int j = 0; j < TOPK; ++j) {
        x0[j] = inputs[(size_t)t * NIN + sj[j]];
        x1[j] = inputs[(size_t)(t + NT) * NIN + sj[j]];
    }
    __syncthreads();

    float a0[HID], a1[HID], c0[HID], c1[HID];

    // ---- layer 1: (6) x (6 x 32) ----
#pragma unroll
    for (int k = 0; k < HID; ++k) { a0[k] = 0.0f; a1[k] = 0.0f; }
#pragma unroll
    for (int j = 0; j < TOPK; ++j) {
        const float v0 = x0[j], v1 = x1[j];
#pragma unroll
        for (int q = 0; q < 8; ++q) {
            float4 w = w1s[j * 8 + q];
            a0[4*q+0] = fmaf(v0, w.x, a0[4*q+0]);
            a0[4*q+1] = fmaf(v0, w.y, a0[4*q+1]);
            a0[4*q+2] = fmaf(v0, w.z, a0[4*q+2]);
            a0[4*q+3] = fmaf(v0, w.w, a0[4*q+3]);
            a1[4*q+0] = fmaf(v1, w.x, a1[4*q+0]);
            a1[4*q+1] = fmaf(v1, w.y, a1[4*q+1]);
            a1[4*q+2] = fmaf(v1, w.z, a1[4*q+2]);
            a1[4*q+3] = fmaf(v1, w.w, a1[4*q+3]);
        }
    }
#pragma unroll
    for (int k = 0; k < HID; ++k) {
        a0[k] = a0[k] > 0.0f ? a0[k] : 0.0f;
        a1[k] = a1[k] > 0.0f ? a1[k] : 0.0f;
    }

    // ---- layer 2: a -> c ----
#pragma unroll
    for (int k = 0; k < HID; ++k) { c0[k] = 0.0f; c1[k] = 0.0f; }
#pragma unroll
    for (int hh = 0; hh < HID; ++hh) {
        const float v0 = a0[hh], v1 = a1[hh];
#pragma unroll
        for (int q = 0; q < 8; ++q) {
            float4 w = w2s[hh * 8 + q];
            c0[4*q+0] = fmaf(v0, w.x, c0[4*q+0]);
            c0[4*q+1] = fmaf(v0, w.y, c0[4*q+1]);
            c0[4*q+2] = fmaf(v0, w.z, c0[4*q+2]);
            c0[4*q+3] = fmaf(v0, w.w, c0[4*q+3]);
            c1[4*q+0] = fmaf(v1, w.x, c1[4*q+0]);
            c1[4*q+1] = fmaf(v1, w.y, c1[4*q+1]);
            c1[4*q+2] = fmaf(v1, w.z, c1[4*q+2]);
            c1[4*q+3] = fmaf(v1, w.w, c1[4*q+3]);
        }
    }
#pragma unroll
    for (int k = 0; k < HID; ++k) {
        c0[k] = c0[k] > 0.0f ? c0[k] : 0.0f;
        c1[k] = c1[k] > 0.0f ? c1[k] : 0.0f;
    }

    // ---- layer 3: c -> a ----
#pragma unroll
    for (int k = 0; k < HID; ++k) { a0[k] = 0.0f; a1[k] = 0.0f; }
#pragma unroll
    for (int hh = 0; hh < HID; ++hh) {
        const float v0 = c0[hh], v1 = c1[hh];
#pragma unroll
        for (int q = 0; q < 8; ++q) {
            float4 w = w3s[hh * 8 + q];
            a0[4*q+0] = fmaf(v0, w.x, a0[4*q+0]);
            a0[4*q+1] = fmaf(v0, w.y, a0[4*q+1]);
            a0[4*q+2] = fmaf(v0, w.z, a0[4*q+2]);
            a0[4*q+3] = fmaf(v0, w.w, a0[4*q+3]);
            a1[4*q+0] = fmaf(v1, w.x, a1[4*q+0]);
            a1[4*q+1] = fmaf(v1, w.y, a1[4*q+1]);
            a1[4*q+2] = fmaf(v1, w.z, a1[4*q+2]);
            a1[4*q+3] = fmaf(v1, w.w, a1[4*q+3]);
        }
    }

    // ---- layer 4: fp64 dot (sign insurance); sigmoid(z)>=0.5 <=> z>=0 ----
    double z0 = 0.0, z1 = 0.0;
#pragma unroll
    for (int q = 0; q < 8; ++q) {
        float4 w = w4s[q];
        float r00 = a0[4*q+0] > 0.0f ? a0[4*q+0] : 0.0f;
        float r01 = a0[4*q+1] > 0.0f ? a0[4*q+1] : 0.0f;
        float r02 = a0[4*q+2] > 0.0f ? a0[4*q+2] : 0.0f;
        float r03 = a0[4*q+3] > 0.0f ? a0[4*q+3] : 0.0f;
        float r10 = a1[4*q+0] > 0.0f ? a1[4*q+0] : 0.0f;
        float r11 = a1[4*q+1] > 0.0f ? a1[4*q+1] : 0.0f;
        float r12 = a1[4*q+2] > 0.0f ? a1[4*q+2] : 0.0f;
        float r13 = a1[4*q+3] > 0.0f ? a1[4*q+3] : 0.0f;
        z0 = fma((double)r00, (double)w.x, z0);
        z0 = fma((double)r01, (double)w.y, z0);
        z0 = fma((double)r02, (double)w.z, z0);
        z0 = fma((double)r03, (double)w.w, z0);
        z1 = fma((double)r10, (double)w.x, z1);
        z1 = fma((double)r11, (double)w.y, z1);
        z1 = fma((double)r12, (double)w.z, z1);
        z1 = fma((double)r13, (double)w.w, z1);
    }

    out[(size_t)t * NOUT + o]        = (z0 >= 0.0) ? 1.0f : -1.0f;
    out[(size_t)(t + NT) * NOUT + o] = (z1 >= 0.0) ? 1.0f : -1.0f;
}

extern "C" void kernel_launch(void* const* d_in, const int* in_sizes, int n_in,
                              void* d_out, int out_size, void* d_ws, size_t ws_size,
                              hipStream_t stream) {
    const float* inputs = (const float*)d_in[0];
    const float* mask   = (const float*)d_in[1];
    const float* W1     = (const float*)d_in[2];
    const float* W2     = (const float*)d_in[3];
    const float* W3     = (const float*)d_in[4];
    const float* W4     = (const float*)d_in[5];
    float* out = (float*)d_out;

    blayer_kernel<<<dim3(NOUT), dim3(NT), 0, stream>>>(
        inputs, mask, W1, W2, W3, W4, out);
}

// Round 4
// 112.323 us; speedup vs baseline: 1.3553x; 1.0786x over previous
//
#include <hip/hip_runtime.h>
#include <math.h>

#define NOUT 512
#define NIN  1024
#define HID  32
#define NB   256
#define TOPK 6
#define HSTR 40   // u16 row stride: 80 B = 16B-aligned for b128, bank-spread

typedef _Float16 f16x8 __attribute__((ext_vector_type(8)));
typedef float    f32x4 __attribute__((ext_vector_type(4)));

union HU  { _Float16 h; unsigned short u; };
union H4U { _Float16 h[4]; unsigned long long u; };
union H8U { _Float16 h[8]; uint4 u; };

__device__ __forceinline__ unsigned short f16bits(float v) {
    HU c; c.h = (_Float16)v; return c.u;
}

// Loads A-frags (NMT m-tiles of W^T) + B-frags (4 n-tiles of H^T) and runs the
// 4-product split-f16 MFMA accumulation. 16x16x32 layouts (m120-verified):
//   A[m=lane&15][k=quad*8+j], B[k=quad*8+j][n=lane&15], D: col=lane&15,row=quad*4+reg.
template<int NMT>
__device__ __forceinline__ void mfma_layer(
    const unsigned short* WtHi, const unsigned short* WtLo,
    const unsigned short* HHi,  const unsigned short* HLo,
    int lane15, int quad, int wb, f32x4 acc[NMT][4])
{
    f16x8 aH[NMT], aL[NMT], bH[4], bL[4];
#pragma unroll
    for (int mt = 0; mt < NMT; ++mt) {
        int off = (mt * 16 + lane15) * HSTR + quad * 8;
        aH[mt] = *(const f16x8*)&WtHi[off];
        aL[mt] = *(const f16x8*)&WtLo[off];
    }
#pragma unroll
    for (int nt = 0; nt < 4; ++nt) {
        int off = (wb + nt * 16 + lane15) * HSTR + quad * 8;
        bH[nt] = *(const f16x8*)&HHi[off];
        bL[nt] = *(const f16x8*)&HLo[off];
    }
#pragma unroll
    for (int mt = 0; mt < NMT; ++mt)
#pragma unroll
        for (int nt = 0; nt < 4; ++nt) {
            acc[mt][nt] = __builtin_amdgcn_mfma_f32_16x16x32_f16(aH[mt], bH[nt], acc[mt][nt], 0, 0, 0);
            acc[mt][nt] = __builtin_amdgcn_mfma_f32_16x16x32_f16(aH[mt], bL[nt], acc[mt][nt], 0, 0, 0);
            acc[mt][nt] = __builtin_amdgcn_mfma_f32_16x16x32_f16(aL[mt], bH[nt], acc[mt][nt], 0, 0, 0);
            acc[mt][nt] = __builtin_amdgcn_mfma_f32_16x16x32_f16(aL[mt], bL[nt], acc[mt][nt], 0, 0, 0);
        }
}

// ReLU + split-f16 + packed b64 store back to H^T (wave-private region).
__device__ __forceinline__ void store_h(
    unsigned short* HHi, unsigned short* HLo,
    int lane15, int quad, int wb, f32x4 acc[2][4])
{
#pragma unroll
    for (int mt = 0; mt < 2; ++mt)
#pragma unroll
        for (int nt = 0; nt < 4; ++nt) {
            H4U hi, lo;
#pragma unroll
            for (int r = 0; r < 4; ++r) {
                float v = acc[mt][nt][r];
                v = v > 0.0f ? v : 0.0f;
                _Float16 h = (_Float16)v;
                hi.h[r] = h;
                lo.h[r] = (_Float16)(v - (float)h);
            }
            int off = (wb + nt * 16 + lane15) * HSTR + mt * 16 + quad * 4;
            *(unsigned long long*)&HHi[off] = hi.u;
            *(unsigned long long*)&HLo[off] = lo.u;
        }
}

__global__ __launch_bounds__(256, 2) void blayer_kernel(
    const float* __restrict__ inputs,  // (B, IN)
    const float* __restrict__ mask,    // (OUT, IN)
    const float* __restrict__ W1,      // (OUT, IN, HID)
    const float* __restrict__ W2,      // (OUT, HID, HID)
    const float* __restrict__ W3,      // (OUT, HID, HID)
    const float* __restrict__ W4,      // (OUT, HID, 1)
    float* __restrict__ out)           // (B, OUT)
{
    const int o = blockIdx.x;
    const int t = threadIdx.x;
    const int l = t & 63, lane15 = l & 15, quad = l >> 4;
    const int wb = (t >> 6) * 64;          // this wave's batch base

    __shared__ __align__(16) unsigned short HtHi[NB * HSTR];   // H^T hi, [b][k]
    __shared__ __align__(16) unsigned short HtLo[NB * HSTR];
    __shared__ __align__(16) unsigned short WHi[3][HID * HSTR]; // W^T for L1..L3, [m][k]
    __shared__ __align__(16) unsigned short WLo[3][HID * HSTR];
    __shared__ __align__(16) unsigned short W4Hi[16 * HSTR];    // row 0 = w4
    __shared__ __align__(16) unsigned short W4Lo[16 * HSTR];
    __shared__ float vals[NIN];
    __shared__ int   sidx[TOPK];
    __shared__ float red_v[4];
    __shared__ int   red_i[4];

    const float* W2g = W2 + (size_t)o * HID * HID;
    const float* W3g = W3 + (size_t)o * HID * HID;
    const float* W4g = W4 + (size_t)o * HID;
    const float* W1g = W1 + (size_t)o * NIN * HID;

    // ---- stage W2/W3/W4 as transposed split-f16 LDS (no top-k dependency) ----
#pragma unroll
    for (int i = 0; i < 4; ++i) {
        int e = t + i * 256, m = e & 31, k = e >> 5;   // Wt[m][k] = W[k][m]
        float v2 = W2g[e], v3 = W3g[e];
        _Float16 h2 = (_Float16)v2, h3 = (_Float16)v3;
        WHi[1][m * HSTR + k] = f16bits(v2);
        WLo[1][m * HSTR + k] = f16bits(v2 - (float)h2);
        WHi[2][m * HSTR + k] = f16bits(v3);
        WLo[2][m * HSTR + k] = f16bits(v3 - (float)h3);
    }
#pragma unroll
    for (int i = 0; i < 2; ++i) {
        int e = t + i * 256, m = e >> 5, k = e & 31;   // 16 rows; row 0 holds w4
        float v = (m == 0) ? W4g[k] : 0.0f;
        _Float16 h = (_Float16)v;
        W4Hi[m * HSTR + k] = f16bits(v);
        W4Lo[m * HSTR + k] = f16bits(v - (float)h);
    }

    // ---- stage mask row ----
    const float* mrow = mask + (size_t)o * NIN;
#pragma unroll
    for (int k = 0; k < NIN / NB; ++k) vals[t + NB * k] = mrow[t + NB * k];
    __syncthreads();

    // ---- top-6 via iterative argmax (verified in rounds 1-3) ----
    for (int it = 0; it < TOPK; ++it) {
        float bv = -INFINITY;
        int   bi = 0;
#pragma unroll
        for (int k = 0; k < NIN / NB; ++k) {
            float v = vals[t + NB * k];
            if (v > bv) { bv = v; bi = t + NB * k; }
        }
#pragma unroll
        for (int off = 32; off > 0; off >>= 1) {
            float ov = __shfl_down(bv, off);
            int   oi = __shfl_down(bi, off);
            if (ov > bv) { bv = ov; bi = oi; }
        }
        if ((t & 63) == 0) { red_v[t >> 6] = bv; red_i[t >> 6] = bi; }
        __syncthreads();
        if (t == 0) {
            float fv = red_v[0]; int fi = red_i[0];
            for (int w = 1; w < 4; ++w)
                if (red_v[w] > fv) { fv = red_v[w]; fi = red_i[w]; }
            sidx[it] = fi;
            vals[fi] = -INFINITY;
        }
        __syncthreads();
    }

    // ---- W1 selected rows, transposed split-f16; k>=6 zero-padded ----
#pragma unroll
    for (int i = 0; i < 4; ++i) {
        int e = t + i * 256, m = e & 31, k = e >> 5;
        float v = (k < TOPK) ? W1g[(size_t)sidx[k] * HID + m] : 0.0f;
        _Float16 h = (_Float16)v;
        WHi[0][m * HSTR + k] = f16bits(v);
        WLo[0][m * HSTR + k] = f16bits(v - (float)h);
    }

    // ---- gather gated inputs into H^T (thread t = batch b), zero-pad k=6..31 ----
    {
        int sj[TOPK];
#pragma unroll
        for (int j = 0; j < TOPK; ++j)
            sj[j] = __builtin_amdgcn_readfirstlane(sidx[j]);
        H8U xh, xl;
#pragma unroll
        for (int j = 0; j < 8; ++j) { xh.h[j] = (_Float16)0.0f; xl.h[j] = (_Float16)0.0f; }
#pragma unroll
        for (int j = 0; j < TOPK; ++j) {
            float v = inputs[(size_t)t * NIN + sj[j]];
            _Float16 h = (_Float16)v;
            xh.h[j] = h;
            xl.h[j] = (_Float16)(v - (float)h);
        }
        *(uint4*)&HtHi[t * HSTR]      = xh.u;
        *(uint4*)&HtLo[t * HSTR]      = xl.u;
        uint4 z = make_uint4(0, 0, 0, 0);
        *(uint4*)&HtHi[t * HSTR + 8]  = z;   // k  8..15
        *(uint4*)&HtHi[t * HSTR + 16] = z;   // k 16..23
        *(uint4*)&HtHi[t * HSTR + 24] = z;   // k 24..31
        *(uint4*)&HtLo[t * HSTR + 8]  = z;
        *(uint4*)&HtLo[t * HSTR + 16] = z;
        *(uint4*)&HtLo[t * HSTR + 24] = z;
    }
    __syncthreads();   // last barrier: Wt visible to all waves; layers are barrier-free

    // ---- layers 1..3: H^T = relu(W^T · H^T), in-place per-wave ----
    f32x4 acc[2][4];
#pragma unroll
    for (int L = 0; L < 3; ++L) {
#pragma unroll
        for (int mt = 0; mt < 2; ++mt)
#pragma unroll
            for (int nt = 0; nt < 4; ++nt) acc[mt][nt] = (f32x4){0.f, 0.f, 0.f, 0.f};
        mfma_layer<2>(&WHi[L][0], &WLo[L][0], HtHi, HtLo, lane15, quad, wb, acc);
        store_h(HtHi, HtLo, lane15, quad, wb, acc);
    }

    // ---- layer 4: z row lives in D row 0 (quad==0, reg 0) ----
    f32x4 acc4[1][4];
#pragma unroll
    for (int nt = 0; nt < 4; ++nt) acc4[0][nt] = (f32x4){0.f, 0.f, 0.f, 0.f};
    mfma_layer<1>(W4Hi, W4Lo, HtHi, HtLo, lane15, quad, wb, acc4);

    if (quad == 0) {
#pragma unroll
        for (int nt = 0; nt < 4; ++nt) {
            int b = wb + nt * 16 + lane15;
            out[(size_t)b * NOUT + o] = (acc4[0][nt][0] >= 0.0f) ? 1.0f : -1.0f;
        }
    }
}

extern "C" void kernel_launch(void* const* d_in, const int* in_sizes, int n_in,
                              void* d_out, int out_size, void* d_ws, size_t ws_size,
                              hipStream_t stream) {
    const float* inputs = (const float*)d_in[0];
    const float* mask   = (const float*)d_in[1];
    const float* W1     = (const float*)d_in[2];
    const float* W2     = (const float*)d_in[3];
    const float* W3     = (const float*)d_in[4];
    const float* W4     = (const float*)d_in[5];
    float* out = (float*)d_out;

    blayer_kernel<<<dim3(NOUT), dim3(NB), 0, stream>>>(
        inputs, mask, W1, W2, W3, W4, out);
}